// Round 8
// baseline (12121.290 us; speedup 1.0000x reference)
//
#include <hip/hip_runtime.h>

typedef unsigned short u16;
typedef unsigned int u32;

__device__ __forceinline__ float bf2f(u16 u) { return __uint_as_float(((u32)u) << 16); }
__device__ __forceinline__ u16 f2bf(float f) {
  u32 u = __float_as_uint(f);
  return (u16)((u + 0x7fffu + ((u >> 16) & 1u)) >> 16);
}

// ---------------------------------------------------------------------------
// Embedding gather: fp32 emb row -> internal bf16 feature row. 1 thread/elem.
__global__ void gather_f2b(const float* __restrict__ emb, const int* __restrict__ ids,
                           u16* __restrict__ out, int n, int V) {
  int u = blockIdx.x * 256 + threadIdx.x;
  if (u >= n * 64) return;
  int node = u >> 6, k = u & 63;
  int r = ids[node];
  r = ((u32)r < (u32)V) ? r : 0;
  out[u] = f2bf(emb[(size_t)r * 64 + k]);
}

// ---------------------------------------------------------------------------
// Degree histogram (guarded)
__global__ void hist_kernel(const int* __restrict__ dst, int* __restrict__ cnt, int E, int N) {
  int e = blockIdx.x * 256 + threadIdx.x;
  if (e < E) {
    int d = dst[e];
    if ((u32)d < (u32)N) atomicAdd(&cnt[d], 1);
  }
}

// Exclusive scan of 5 degree arrays -> CSR offsets. grid = 5 blocks x 1024.
__global__ void __launch_bounds__(1024) scan5_kernel(const int* __restrict__ cnt,
                                                     int* __restrict__ off,
                                                     int n0, int n1, int n2, int n3, int n4) {
  int Ns[5] = {n0, n1, n2, n3, n4};
  int r = blockIdx.x;
  int cOff = 0, oOff = 0;
  for (int i = 0; i < r; i++) { cOff += Ns[i]; oOff += Ns[i] + 1; }
  const int* c = cnt + cOff;
  int* of = off + oOff;
  int N = Ns[r];
  __shared__ int wsum[16];
  int t = threadIdx.x, lane = t & 63, wave = t >> 6;
  int carry = 0;
  for (int base = 0; base < N; base += 1024) {
    int i = base + t;
    int v = (i < N) ? c[i] : 0;
    int s = v;
    #pragma unroll
    for (int d = 1; d < 64; d <<= 1) {
      int u = __shfl_up(s, d);
      if (lane >= d) s += u;
    }
    if (lane == 63) wsum[wave] = s;
    __syncthreads();
    if (wave == 0) {
      int v2 = (lane < 16) ? wsum[lane] : 0;
      #pragma unroll
      for (int d = 1; d < 16; d <<= 1) {
        int u = __shfl_up(v2, d);
        if (lane >= d) v2 += u;
      }
      if (lane < 16) wsum[lane] = v2;
    }
    __syncthreads();
    int wbase = wave ? wsum[wave - 1] : 0;
    if (i < N) of[i] = carry + wbase + (s - v);
    int tot = wsum[15];
    __syncthreads();
    carry += tot;
  }
  if (t == 0) of[N] = carry;
}

// CSR fill (guarded): idxOut[off[dst]+cursor++] = src
__global__ void fill_kernel(const int* __restrict__ src, const int* __restrict__ dst,
                            const int* __restrict__ off, int* __restrict__ cur,
                            int* __restrict__ idxOut, int E, int N) {
  int e = blockIdx.x * 256 + threadIdx.x;
  if (e < E) {
    int d = dst[e];
    if ((u32)d < (u32)N) {
      int pos = off[d] + atomicAdd(&cur[d], 1);
      if ((u32)pos < (u32)E) idxOut[pos] = src[e];
    }
  }
}

// ---------------------------------------------------------------------------
// SAGE layer, one WAVE per destination node; weights read RAW from fp32
// inputs (inline transpose into LDS).
//   acc[o] = sum_a mean_a @ Wl[lt][ra].T + x @ (sum_a Wr[lt][ra]).T
//   out = relu((acc + sum_a bl[lt][ra]) * scale) + x     (bf16 in/out, fp32 math)
__global__ void __launch_bounds__(256) sage_node(
    const u16* __restrict__ xin, u16* __restrict__ xout, int n_dst, float scale,
    const float* __restrict__ Wl, const float* __restrict__ bl, const float* __restrict__ Wr,
    int lt, int nAgg, int4 rels,
    const u16* s0, const int* of0, const int* ix0, int ns0,
    const u16* s1, const int* of1, const int* ix1, int ns1,
    const u16* s2, const int* of2, const int* ix2, int ns2) {
  __shared__ float Wsh[4096];      // W^T[k][o]
  __shared__ float rows[4][64];
  int t = threadIdx.x, wave = t >> 6, lane = t & 63;
  int g = blockIdx.x * 4 + wave;
  float acc = 0.f;

  const u16* S[3] = {s0, s1, s2};
  const int* OF[3] = {of0, of1, of2};
  const int* IX[3] = {ix0, ix1, ix2};
  int NS[3] = {ns0, ns1, ns2};
  int RR[3] = {rels.x, rels.y, rels.z};

  for (int a = 0; a < nAgg; a++) {
    int r = RR[a];
    size_t wbase = ((size_t)lt * 5 + r) * 4096;    // Wl[lt][r] flat (o*64+k)
    __syncthreads();
    #pragma unroll
    for (int i = 0; i < 16; i++) {
      int d = t + i * 256;
      int k = d >> 6, o = d & 63;
      Wsh[d] = Wl[wbase + (size_t)o * 64 + k];     // Wsh[k][o] = Wl[o][k]
    }
    float m = 0.f;
    if (g < n_dst) {
      const int* off = OF[a];
      const int* idx = IX[a];
      const u16* src = S[a];
      u32 ns = (u32)NS[a];
      int e0 = off[g], e1 = off[g + 1];
      for (int e = e0; e < e1; e++) {
        int A = idx[e];
        A = ((u32)A < ns) ? A : 0;
        m += bf2f(src[(size_t)A * 64 + lane]);
      }
      int dn = e1 - e0;
      if (dn > 0) m /= (float)dn;
    }
    rows[wave][lane] = m;
    __syncthreads();
    float s = 0.f;
    for (int k = 0; k < 64; k++) s += rows[wave][k] * Wsh[(k << 6) + lane];
    acc += s;
  }

  // root term: Wsh = sum over used relations of Wr[lt][r]^T
  __syncthreads();
  #pragma unroll
  for (int i = 0; i < 16; i++) {
    int d = t + i * 256;
    int k = d >> 6, o = d & 63;
    float w = 0.f;
    for (int a = 0; a < nAgg; a++)
      w += Wr[((size_t)lt * 5 + RR[a]) * 4096 + (size_t)o * 64 + k];
    Wsh[d] = w;
  }
  float xv = (g < n_dst) ? bf2f(xin[(size_t)g * 64 + lane]) : 0.f;
  rows[wave][lane] = xv;
  __syncthreads();
  float s = 0.f;
  for (int k = 0; k < 64; k++) s += rows[wave][k] * Wsh[(k << 6) + lane];
  acc += s;

  float bsum = 0.f;
  for (int a = 0; a < nAgg; a++)
    bsum += bl[((size_t)lt * 5 + RR[a]) * 64 + lane];

  if (g < n_dst) {
    float v = fmaxf((acc + bsum) * scale, 0.f) + xv;
    xout[(size_t)g * 64 + lane] = f2bf(v);
  }
}

// ---------------------------------------------------------------------------
// Column sums over bf16 features (graph-mean readout)
__global__ void colsum2(const u16* __restrict__ x, int n, float* __restrict__ gout) {
  __shared__ float part[64];
  int t = threadIdx.x;
  if (t < 64) part[t] = 0.f;
  __syncthreads();
  int col = t & 63, w = blockIdx.x * 4 + (t >> 6), tw = gridDim.x * 4;
  float s = 0.f;
  for (int r = w; r < n; r += tw) s += bf2f(x[(size_t)r * 64 + col]);
  atomicAdd(&part[col], s);
  __syncthreads();
  if (t < 64) atomicAdd(&gout[t], part[t]);
}

// Crime head: out[0:20) as FP32
__global__ void __launch_bounds__(256) head2(const float* __restrict__ gsum,
    const float* __restrict__ Wc1, const float* __restrict__ bc1,
    const float* __restrict__ Wc2, const float* __restrict__ bc2,
    int NP, int NO, int NL, float* __restrict__ out) {
  __shared__ float g[192];
  __shared__ float h[64];
  int t = threadIdx.x;
  if (t < 192) {
    float d = (t < 64) ? (float)NP : (t < 128) ? (float)NO : (float)NL;
    g[t] = gsum[t] / d;
  }
  __syncthreads();
  if (t < 64) {
    float a = bc1[t];
    for (int k = 0; k < 192; k++) a += g[k] * Wc1[(size_t)t * 192 + k];
    h[t] = fmaxf(a, 0.f);
  }
  __syncthreads();
  if (t < 20) {
    float a = bc2[t];
    for (int k = 0; k < 64; k++) a += h[k] * Wc2[(size_t)t * 64 + k];
    out[t] = a;
  }
}

// Suspect head: out[i] as FP32 (out passed pre-offset by +20)
__global__ void __launch_bounds__(256) suspect2(const u16* __restrict__ p,
    const float* __restrict__ Ws1, const float* __restrict__ bs1,
    const float* __restrict__ Ws2, const float* __restrict__ bs2,
    float* __restrict__ out, int NP) {
  __shared__ float W1[2048];       // raw layout [j*64+k]
  __shared__ float b1[32], w2[32];
  __shared__ float b2s;
  int t = threadIdx.x;
  #pragma unroll
  for (int i = 0; i < 8; i++) {
    int d = t + i * 256;
    W1[d] = Ws1[d];
  }
  if (t < 32) { b1[t] = bs1[t]; w2[t] = Ws2[t]; }
  if (t == 0) b2s = bs2[0];
  __syncthreads();
  int i = blockIdx.x * 256 + t;
  if (i >= NP) return;
  float x[64];
  #pragma unroll
  for (int k = 0; k < 64; k++) x[k] = bf2f(p[(size_t)i * 64 + k]);
  float sc = b2s;
  for (int j = 0; j < 32; j++) {
    float a = b1[j];
    const float* wr = &W1[j * 64];
    #pragma unroll
    for (int k = 0; k < 64; k++) a += x[k] * wr[k];
    sc += fmaxf(a, 0.f) * w2[j];
  }
  out[i] = sc;
}

// ---------------------------------------------------------------------------
extern "C" void kernel_launch(void* const* d_in, const int* in_sizes, int n_in,
                              void* d_out, int out_size, void* d_ws, size_t ws_size,
                              hipStream_t stream) {
  const int NP = in_sizes[0], NO = in_sizes[1], NL = in_sizes[2];
  const int Ea = in_sizes[3], Eu = in_sizes[5], Et = in_sizes[7];
  const int VP = in_sizes[9] / 64, VO = in_sizes[10] / 64, VL = in_sizes[11] / 64;

  const int* x_person   = (const int*)d_in[0];
  const int* x_object   = (const int*)d_in[1];
  const int* x_location = (const int*)d_in[2];
  const int* acts_src = (const int*)d_in[3];
  const int* acts_dst = (const int*)d_in[4];
  const int* uses_src = (const int*)d_in[5];
  const int* uses_dst = (const int*)d_in[6];
  const int* at_src   = (const int*)d_in[7];
  const int* at_dst   = (const int*)d_in[8];
  const float* person_emb   = (const float*)d_in[9];
  const float* object_emb   = (const float*)d_in[10];
  const float* location_emb = (const float*)d_in[11];
  const float* Wl  = (const float*)d_in[12];
  const float* bl  = (const float*)d_in[13];
  const float* Wr  = (const float*)d_in[14];
  const float* Wc1 = (const float*)d_in[15];
  const float* bc1 = (const float*)d_in[16];
  const float* Wc2 = (const float*)d_in[17];
  const float* bc2 = (const float*)d_in[18];
  const float* Ws1 = (const float*)d_in[19];
  const float* bs1 = (const float*)d_in[20];
  const float* Ws2 = (const float*)d_in[21];
  const float* bs2 = (const float*)d_in[22];
  float* out = (float*)d_out;     // reference output dtype is float32

  // ---- workspace (16B aligned) — ~112 MB ----
  char* w = (char*)d_ws;
  auto alloc = [&](size_t bytes) { char* r = w; w += (bytes + 15) & ~(size_t)15; return r; };
  u16* pA = (u16*)alloc((size_t)NP * 64 * 2);
  u16* pB = (u16*)alloc((size_t)NP * 64 * 2);
  u16* oA = (u16*)alloc((size_t)NO * 64 * 2);
  u16* oB = (u16*)alloc((size_t)NO * 64 * 2);
  u16* lA = (u16*)alloc((size_t)NL * 64 * 2);
  u16* lB = (u16*)alloc((size_t)NL * 64 * 2);
  float* gsum = (float*)alloc(192 * 4);
  const size_t CN = (size_t)3 * NP + NO + NL;
  int* cnt = (int*)alloc(CN * 4);
  int* cur = (int*)alloc(CN * 4);
  int* off = (int*)alloc((CN + 8) * 4);
  int* csr = (int*)alloc(((size_t)Ea + 2 * (size_t)Eu + 2 * (size_t)Et) * 4);
  (void)n_in; (void)out_size;
  // ws guard: if it fires, out stays 0 -> absmax == 0.118652 exactly (signature)
  if ((size_t)(w - (char*)d_ws) > ws_size) return;

  // slots: 0=acts(by acts_dst,NP) 1=uses fwd(by uses_dst,NO)
  //        2=uses rev(by uses_src,NP) 3=at fwd(by at_dst,NL) 4=at rev(by at_src,NP)
  int c0 = 0, c1 = NP, c2 = NP + NO, c3 = 2 * NP + NO, c4 = 2 * NP + NO + NL;
  int o0 = 0, o1 = NP + 1, o2 = o1 + NO + 1, o3 = o2 + NP + 1, o4 = o3 + NL + 1;
  int* csr0 = csr;
  int* csr1 = csr0 + Ea;
  int* csr2 = csr1 + Eu;
  int* csr3 = csr2 + Eu;
  int* csr4 = csr3 + Et;

  hipMemsetAsync(cnt, 0, CN * 2 * sizeof(int), stream);  // cnt + cur adjacent
  hipMemsetAsync(gsum, 0, 192 * sizeof(float), stream);

  gather_f2b<<<(NP * 64 + 255) / 256, 256, 0, stream>>>(person_emb, x_person, pA, NP, VP);
  gather_f2b<<<(NO * 64 + 255) / 256, 256, 0, stream>>>(object_emb, x_object, oA, NO, VO);
  gather_f2b<<<(NL * 64 + 255) / 256, 256, 0, stream>>>(location_emb, x_location, lA, NL, VL);

  int gbEa = (Ea + 255) / 256, gbEu = (Eu + 255) / 256, gbEt = (Et + 255) / 256;
  hist_kernel<<<gbEa, 256, 0, stream>>>(acts_dst, cnt + c0, Ea, NP);
  hist_kernel<<<gbEu, 256, 0, stream>>>(uses_dst, cnt + c1, Eu, NO);
  hist_kernel<<<gbEu, 256, 0, stream>>>(uses_src, cnt + c2, Eu, NP);
  hist_kernel<<<gbEt, 256, 0, stream>>>(at_dst,   cnt + c3, Et, NL);
  hist_kernel<<<gbEt, 256, 0, stream>>>(at_src,   cnt + c4, Et, NP);

  scan5_kernel<<<5, 1024, 0, stream>>>(cnt, off, NP, NO, NP, NL, NP);

  fill_kernel<<<gbEa, 256, 0, stream>>>(acts_src, acts_dst, off + o0, cur + c0, csr0, Ea, NP);
  fill_kernel<<<gbEu, 256, 0, stream>>>(uses_src, uses_dst, off + o1, cur + c1, csr1, Eu, NO);
  fill_kernel<<<gbEu, 256, 0, stream>>>(uses_dst, uses_src, off + o2, cur + c2, csr2, Eu, NP);
  fill_kernel<<<gbEt, 256, 0, stream>>>(at_src,   at_dst,   off + o3, cur + c3, csr3, Et, NL);
  fill_kernel<<<gbEt, 256, 0, stream>>>(at_dst,   at_src,   off + o4, cur + c4, csr4, Et, NP);

  // ---- 3 layers (ping-pong bf16 features), one wave per node ----
  u16* pb[2] = {pA, pB};
  u16* ob[2] = {oA, oB};
  u16* lb[2] = {lA, lB};
  int bP = (NP + 3) / 4, bO = (NO + 3) / 4, bL = (NL + 3) / 4;
  int cu = 0;
  int4 relsP = {0, 2, 4, 0}, relsO = {1, 0, 0, 0}, relsL = {3, 0, 0, 0};
  for (int t = 0; t < 3; t++) {
    u16 *pi = pb[cu], *po = pb[1 - cu];
    u16 *oi = ob[cu], *oo = ob[1 - cu];
    u16 *li = lb[cu], *lo = lb[1 - cu];
    sage_node<<<bP, 256, 0, stream>>>(pi, po, NP, 1.f / 3.f, Wl, bl, Wr, t, 3, relsP,
        pi, off + o0, csr0, NP,
        oi, off + o2, csr2, NO,
        li, off + o4, csr4, NL);
    sage_node<<<bO, 256, 0, stream>>>(oi, oo, NO, 1.f, Wl, bl, Wr, t, 1, relsO,
        pi, off + o1, csr1, NP,
        (const u16*)0, (const int*)0, (const int*)0, 0,
        (const u16*)0, (const int*)0, (const int*)0, 0);
    sage_node<<<bL, 256, 0, stream>>>(li, lo, NL, 1.f, Wl, bl, Wr, t, 1, relsL,
        pi, off + o3, csr3, NP,
        (const u16*)0, (const int*)0, (const int*)0, 0,
        (const u16*)0, (const int*)0, (const int*)0, 0);
    cu = 1 - cu;
  }
  u16* pF = pb[cu];
  u16* oF = ob[cu];
  u16* lF = lb[cu];

  // ---- readout (FP32 output) ----
  colsum2<<<512, 256, 0, stream>>>(pF, NP, gsum);
  colsum2<<<512, 256, 0, stream>>>(oF, NO, gsum + 64);
  colsum2<<<256, 256, 0, stream>>>(lF, NL, gsum + 128);
  head2<<<1, 256, 0, stream>>>(gsum, Wc1, bc1, Wc2, bc2, NP, NO, NL, out);
  suspect2<<<(NP + 255) / 256, 256, 0, stream>>>(pF, Ws1, bs1, Ws2, bs2, out + 20, NP);
}

// Round 9
// 5036.208 us; speedup vs baseline: 2.4068x; 2.4068x over previous
//
#include <hip/hip_runtime.h>

typedef unsigned short u16;
typedef unsigned int u32;

__device__ __forceinline__ float bf2f(u16 u) { return __uint_as_float(((u32)u) << 16); }
__device__ __forceinline__ u16 f2bf(float f) {
  u32 u = __float_as_uint(f);
  return (u16)((u + 0x7fffu + ((u >> 16) & 1u)) >> 16);
}

// ---------------------------------------------------------------------------
// Embedding gather: fp32 emb row -> internal bf16 feature row. 1 thread/elem.
__global__ void gather_f2b(const float* __restrict__ emb, const int* __restrict__ ids,
                           u16* __restrict__ out, int n, int V) {
  int u = blockIdx.x * 256 + threadIdx.x;
  if (u >= n * 64) return;
  int node = u >> 6, k = u & 63;
  int r = ids[node];
  r = ((u32)r < (u32)V) ? r : 0;
  out[u] = f2bf(emb[(size_t)r * 64 + k]);
}

// ---------------------------------------------------------------------------
// Degree histogram (guarded)
__global__ void hist_kernel(const int* __restrict__ dst, int* __restrict__ cnt, int E, int N) {
  int e = blockIdx.x * 256 + threadIdx.x;
  if (e < E) {
    int d = dst[e];
    if ((u32)d < (u32)N) atomicAdd(&cnt[d], 1);
  }
}

// Exclusive scan of 5 degree arrays -> CSR offsets. grid = 5 blocks x 1024.
__global__ void __launch_bounds__(1024) scan5_kernel(const int* __restrict__ cnt,
                                                     int* __restrict__ off,
                                                     int n0, int n1, int n2, int n3, int n4) {
  int Ns[5] = {n0, n1, n2, n3, n4};
  int r = blockIdx.x;
  int cOff = 0, oOff = 0;
  for (int i = 0; i < r; i++) { cOff += Ns[i]; oOff += Ns[i] + 1; }
  const int* c = cnt + cOff;
  int* of = off + oOff;
  int N = Ns[r];
  __shared__ int wsum[16];
  int t = threadIdx.x, lane = t & 63, wave = t >> 6;
  int carry = 0;
  for (int base = 0; base < N; base += 1024) {
    int i = base + t;
    int v = (i < N) ? c[i] : 0;
    int s = v;
    #pragma unroll
    for (int d = 1; d < 64; d <<= 1) {
      int u = __shfl_up(s, d);
      if (lane >= d) s += u;
    }
    if (lane == 63) wsum[wave] = s;
    __syncthreads();
    if (wave == 0) {
      int v2 = (lane < 16) ? wsum[lane] : 0;
      #pragma unroll
      for (int d = 1; d < 16; d <<= 1) {
        int u = __shfl_up(v2, d);
        if (lane >= d) v2 += u;
      }
      if (lane < 16) wsum[lane] = v2;
    }
    __syncthreads();
    int wbase = wave ? wsum[wave - 1] : 0;
    if (i < N) of[i] = carry + wbase + (s - v);
    int tot = wsum[15];
    __syncthreads();
    carry += tot;
  }
  if (t == 0) of[N] = carry;
}

// CSR fill (guarded): idxOut[off[dst]+cursor++] = src
__global__ void fill_kernel(const int* __restrict__ src, const int* __restrict__ dst,
                            const int* __restrict__ off, int* __restrict__ cur,
                            int* __restrict__ idxOut, int E, int N) {
  int e = blockIdx.x * 256 + threadIdx.x;
  if (e < E) {
    int d = dst[e];
    if ((u32)d < (u32)N) {
      int pos = off[d] + atomicAdd(&cur[d], 1);
      if ((u32)pos < (u32)E) idxOut[pos] = src[e];
    }
  }
}

// ---------------------------------------------------------------------------
// Mean-gather one node's neighborhood with 4-wide ILP (independent partial
// sums keep 4 row loads in flight — this is the latency fix).
__device__ __forceinline__ float gmean(const u16* __restrict__ src, const int* __restrict__ off,
                                       const int* __restrict__ idx, u32 ns, int g, int lane) {
  int e0 = off[g], e1 = off[g + 1];
  float a0 = 0.f, a1 = 0.f, a2 = 0.f, a3 = 0.f;
  int e = e0;
  for (; e + 4 <= e1; e += 4) {
    int A = idx[e], B = idx[e + 1], C = idx[e + 2], D = idx[e + 3];
    A = ((u32)A < ns) ? A : 0;
    B = ((u32)B < ns) ? B : 0;
    C = ((u32)C < ns) ? C : 0;
    D = ((u32)D < ns) ? D : 0;
    a0 += bf2f(src[(size_t)A * 64 + lane]);
    a1 += bf2f(src[(size_t)B * 64 + lane]);
    a2 += bf2f(src[(size_t)C * 64 + lane]);
    a3 += bf2f(src[(size_t)D * 64 + lane]);
  }
  for (; e < e1; e++) {
    int A = idx[e];
    A = ((u32)A < ns) ? A : 0;
    a0 += bf2f(src[(size_t)A * 64 + lane]);
  }
  float s = (a0 + a1) + (a2 + a3);
  int d = e1 - e0;
  return (d > 0) ? s * (1.f / (float)d) : 0.f;
}

// Coalesced float4 load of one 64x64 weight matrix into LDS [o][k] pitch 65.
// Dot-read pattern Wsh[lane*65+k]: bank (lane+k)%32 -> 2-way aliasing (free).
__device__ __forceinline__ void stageW(float* __restrict__ Wsh, const float* __restrict__ Wb,
                                       int t) {
  #pragma unroll
  for (int j = 0; j < 4; j++) {
    int i4 = t + j * 256;                      // float4 index (0..1023)
    float4 v = ((const float4*)Wb)[i4];        // coalesced 16B/lane
    int o = (i4 * 4) >> 6, k = (i4 * 4) & 63;  // same o-row for all 4 floats
    float* dst = &Wsh[o * 65 + k];
    dst[0] = v.x; dst[1] = v.y; dst[2] = v.z; dst[3] = v.w;
  }
}

// ---------------------------------------------------------------------------
// SAGE layer, one WAVE per destination node.
// Phase 1 (no barriers): ILP-4 mean-gathers for all relations + root row.
// Phase 2: per relation, stage W coalesced -> LDS, dot via __shfl broadcast.
__global__ void __launch_bounds__(256) sage_node(
    const u16* __restrict__ xin, u16* __restrict__ xout, int n_dst, float scale,
    const float* __restrict__ Wl, const float* __restrict__ bl, const float* __restrict__ Wr,
    int lt, int nAgg, int4 rels,
    const u16* s0, const int* of0, const int* ix0, int ns0,
    const u16* s1, const int* of1, const int* ix1, int ns1,
    const u16* s2, const int* of2, const int* ix2, int ns2) {
  __shared__ float Wsh[64 * 65];
  int t = threadIdx.x, wave = t >> 6, lane = t & 63;
  int g = blockIdx.x * 4 + wave;
  bool act = g < n_dst;

  // ---- gather phase: barrier-free, maximum memory-level parallelism ----
  float m0 = act ? gmean(s0, of0, ix0, (u32)ns0, g, lane) : 0.f;
  float m1 = (act && nAgg > 1) ? gmean(s1, of1, ix1, (u32)ns1, g, lane) : 0.f;
  float m2 = (act && nAgg > 2) ? gmean(s2, of2, ix2, (u32)ns2, g, lane) : 0.f;
  float xv = act ? bf2f(xin[(size_t)g * 64 + lane]) : 0.f;

  float acc = 0.f;
  // ---- relation GEMM phases ----
  for (int p = 0; p < nAgg; p++) {
    int r = (p == 0) ? rels.x : (p == 1) ? rels.y : rels.z;
    const float* Wb = Wl + ((size_t)lt * 5 + r) * 4096;
    __syncthreads();               // previous Wsh fully consumed
    stageW(Wsh, Wb, t);
    __syncthreads();
    float mv = (p == 0) ? m0 : (p == 1) ? m1 : m2;
    #pragma unroll
    for (int k = 0; k < 64; k++)
      acc += __shfl(mv, k) * Wsh[lane * 65 + k];
  }

  // ---- root phase: Wsh = sum of Wr over used relations ----
  {
    const float* w0 = Wr + ((size_t)lt * 5 + rels.x) * 4096;
    const float* w1 = Wr + ((size_t)lt * 5 + rels.y) * 4096;
    const float* w2 = Wr + ((size_t)lt * 5 + rels.z) * 4096;
    __syncthreads();
    #pragma unroll
    for (int j = 0; j < 4; j++) {
      int i4 = t + j * 256;
      float4 v = ((const float4*)w0)[i4];
      if (nAgg > 1) {
        float4 b = ((const float4*)w1)[i4];
        float4 c = ((const float4*)w2)[i4];
        v.x += b.x + c.x; v.y += b.y + c.y; v.z += b.z + c.z; v.w += b.w + c.w;
      }
      int o = (i4 * 4) >> 6, k = (i4 * 4) & 63;
      float* dst = &Wsh[o * 65 + k];
      dst[0] = v.x; dst[1] = v.y; dst[2] = v.z; dst[3] = v.w;
    }
    __syncthreads();
    #pragma unroll
    for (int k = 0; k < 64; k++)
      acc += __shfl(xv, k) * Wsh[lane * 65 + k];
  }

  float bsum = bl[((size_t)lt * 5 + rels.x) * 64 + lane];
  if (nAgg > 1) bsum += bl[((size_t)lt * 5 + rels.y) * 64 + lane] +
                        bl[((size_t)lt * 5 + rels.z) * 64 + lane];

  if (act) {
    float v = fmaxf((acc + bsum) * scale, 0.f) + xv;
    xout[(size_t)g * 64 + lane] = f2bf(v);
  }
}

// ---------------------------------------------------------------------------
// Column sums over bf16 features (graph-mean readout)
__global__ void colsum2(const u16* __restrict__ x, int n, float* __restrict__ gout) {
  __shared__ float part[64];
  int t = threadIdx.x;
  if (t < 64) part[t] = 0.f;
  __syncthreads();
  int col = t & 63, w = blockIdx.x * 4 + (t >> 6), tw = gridDim.x * 4;
  float s = 0.f;
  for (int r = w; r < n; r += tw) s += bf2f(x[(size_t)r * 64 + col]);
  atomicAdd(&part[col], s);
  __syncthreads();
  if (t < 64) atomicAdd(&gout[t], part[t]);
}

// Crime head: out[0:20) as FP32
__global__ void __launch_bounds__(256) head2(const float* __restrict__ gsum,
    const float* __restrict__ Wc1, const float* __restrict__ bc1,
    const float* __restrict__ Wc2, const float* __restrict__ bc2,
    int NP, int NO, int NL, float* __restrict__ out) {
  __shared__ float g[192];
  __shared__ float h[64];
  int t = threadIdx.x;
  if (t < 192) {
    float d = (t < 64) ? (float)NP : (t < 128) ? (float)NO : (float)NL;
    g[t] = gsum[t] / d;
  }
  __syncthreads();
  if (t < 64) {
    float a = bc1[t];
    for (int k = 0; k < 192; k++) a += g[k] * Wc1[(size_t)t * 192 + k];
    h[t] = fmaxf(a, 0.f);
  }
  __syncthreads();
  if (t < 20) {
    float a = bc2[t];
    for (int k = 0; k < 64; k++) a += h[k] * Wc2[(size_t)t * 64 + k];
    out[t] = a;
  }
}

// Suspect head: out[i] as FP32 (out passed pre-offset by +20)
__global__ void __launch_bounds__(256) suspect2(const u16* __restrict__ p,
    const float* __restrict__ Ws1, const float* __restrict__ bs1,
    const float* __restrict__ Ws2, const float* __restrict__ bs2,
    float* __restrict__ out, int NP) {
  __shared__ float W1[2048];       // raw layout [j*64+k]
  __shared__ float b1[32], w2[32];
  __shared__ float b2s;
  int t = threadIdx.x;
  #pragma unroll
  for (int i = 0; i < 8; i++) {
    int d = t + i * 256;
    W1[d] = Ws1[d];
  }
  if (t < 32) { b1[t] = bs1[t]; w2[t] = Ws2[t]; }
  if (t == 0) b2s = bs2[0];
  __syncthreads();
  int i = blockIdx.x * 256 + t;
  if (i >= NP) return;
  float x[64];
  #pragma unroll
  for (int k = 0; k < 64; k++) x[k] = bf2f(p[(size_t)i * 64 + k]);
  float sc = b2s;
  for (int j = 0; j < 32; j++) {
    float a = b1[j];
    const float* wr = &W1[j * 64];
    #pragma unroll
    for (int k = 0; k < 64; k++) a += x[k] * wr[k];
    sc += fmaxf(a, 0.f) * w2[j];
  }
  out[i] = sc;
}

// ---------------------------------------------------------------------------
extern "C" void kernel_launch(void* const* d_in, const int* in_sizes, int n_in,
                              void* d_out, int out_size, void* d_ws, size_t ws_size,
                              hipStream_t stream) {
  const int NP = in_sizes[0], NO = in_sizes[1], NL = in_sizes[2];
  const int Ea = in_sizes[3], Eu = in_sizes[5], Et = in_sizes[7];
  const int VP = in_sizes[9] / 64, VO = in_sizes[10] / 64, VL = in_sizes[11] / 64;

  const int* x_person   = (const int*)d_in[0];
  const int* x_object   = (const int*)d_in[1];
  const int* x_location = (const int*)d_in[2];
  const int* acts_src = (const int*)d_in[3];
  const int* acts_dst = (const int*)d_in[4];
  const int* uses_src = (const int*)d_in[5];
  const int* uses_dst = (const int*)d_in[6];
  const int* at_src   = (const int*)d_in[7];
  const int* at_dst   = (const int*)d_in[8];
  const float* person_emb   = (const float*)d_in[9];
  const float* object_emb   = (const float*)d_in[10];
  const float* location_emb = (const float*)d_in[11];
  const float* Wl  = (const float*)d_in[12];
  const float* bl  = (const float*)d_in[13];
  const float* Wr  = (const float*)d_in[14];
  const float* Wc1 = (const float*)d_in[15];
  const float* bc1 = (const float*)d_in[16];
  const float* Wc2 = (const float*)d_in[17];
  const float* bc2 = (const float*)d_in[18];
  const float* Ws1 = (const float*)d_in[19];
  const float* bs1 = (const float*)d_in[20];
  const float* Ws2 = (const float*)d_in[21];
  const float* bs2 = (const float*)d_in[22];
  float* out = (float*)d_out;     // reference output dtype is float32

  // ---- workspace (16B aligned) — ~112 MB ----
  char* w = (char*)d_ws;
  auto alloc = [&](size_t bytes) { char* r = w; w += (bytes + 15) & ~(size_t)15; return r; };
  u16* pA = (u16*)alloc((size_t)NP * 64 * 2);
  u16* pB = (u16*)alloc((size_t)NP * 64 * 2);
  u16* oA = (u16*)alloc((size_t)NO * 64 * 2);
  u16* oB = (u16*)alloc((size_t)NO * 64 * 2);
  u16* lA = (u16*)alloc((size_t)NL * 64 * 2);
  u16* lB = (u16*)alloc((size_t)NL * 64 * 2);
  float* gsum = (float*)alloc(192 * 4);
  const size_t CN = (size_t)3 * NP + NO + NL;
  int* cnt = (int*)alloc(CN * 4);
  int* cur = (int*)alloc(CN * 4);
  int* off = (int*)alloc((CN + 8) * 4);
  int* csr = (int*)alloc(((size_t)Ea + 2 * (size_t)Eu + 2 * (size_t)Et) * 4);
  (void)n_in; (void)out_size;
  // ws guard: if it fires, out stays 0 -> absmax == 0.118652 exactly (signature)
  if ((size_t)(w - (char*)d_ws) > ws_size) return;

  // slots: 0=acts(by acts_dst,NP) 1=uses fwd(by uses_dst,NO)
  //        2=uses rev(by uses_src,NP) 3=at fwd(by at_dst,NL) 4=at rev(by at_src,NP)
  int c0 = 0, c1 = NP, c2 = NP + NO, c3 = 2 * NP + NO, c4 = 2 * NP + NO + NL;
  int o0 = 0, o1 = NP + 1, o2 = o1 + NO + 1, o3 = o2 + NP + 1, o4 = o3 + NL + 1;
  int* csr0 = csr;
  int* csr1 = csr0 + Ea;
  int* csr2 = csr1 + Eu;
  int* csr3 = csr2 + Eu;
  int* csr4 = csr3 + Et;

  hipMemsetAsync(cnt, 0, CN * 2 * sizeof(int), stream);  // cnt + cur adjacent
  hipMemsetAsync(gsum, 0, 192 * sizeof(float), stream);

  gather_f2b<<<(NP * 64 + 255) / 256, 256, 0, stream>>>(person_emb, x_person, pA, NP, VP);
  gather_f2b<<<(NO * 64 + 255) / 256, 256, 0, stream>>>(object_emb, x_object, oA, NO, VO);
  gather_f2b<<<(NL * 64 + 255) / 256, 256, 0, stream>>>(location_emb, x_location, lA, NL, VL);

  int gbEa = (Ea + 255) / 256, gbEu = (Eu + 255) / 256, gbEt = (Et + 255) / 256;
  hist_kernel<<<gbEa, 256, 0, stream>>>(acts_dst, cnt + c0, Ea, NP);
  hist_kernel<<<gbEu, 256, 0, stream>>>(uses_dst, cnt + c1, Eu, NO);
  hist_kernel<<<gbEu, 256, 0, stream>>>(uses_src, cnt + c2, Eu, NP);
  hist_kernel<<<gbEt, 256, 0, stream>>>(at_dst,   cnt + c3, Et, NL);
  hist_kernel<<<gbEt, 256, 0, stream>>>(at_src,   cnt + c4, Et, NP);

  scan5_kernel<<<5, 1024, 0, stream>>>(cnt, off, NP, NO, NP, NL, NP);

  fill_kernel<<<gbEa, 256, 0, stream>>>(acts_src, acts_dst, off + o0, cur + c0, csr0, Ea, NP);
  fill_kernel<<<gbEu, 256, 0, stream>>>(uses_src, uses_dst, off + o1, cur + c1, csr1, Eu, NO);
  fill_kernel<<<gbEu, 256, 0, stream>>>(uses_dst, uses_src, off + o2, cur + c2, csr2, Eu, NP);
  fill_kernel<<<gbEt, 256, 0, stream>>>(at_src,   at_dst,   off + o3, cur + c3, csr3, Et, NL);
  fill_kernel<<<gbEt, 256, 0, stream>>>(at_dst,   at_src,   off + o4, cur + c4, csr4, Et, NP);

  // ---- 3 layers (ping-pong bf16 features), one wave per node ----
  u16* pb[2] = {pA, pB};
  u16* ob[2] = {oA, oB};
  u16* lb[2] = {lA, lB};
  int bP = (NP + 3) / 4, bO = (NO + 3) / 4, bL = (NL + 3) / 4;
  int cu = 0;
  int4 relsP = {0, 2, 4, 0}, relsO = {1, 1, 1, 0}, relsL = {3, 3, 3, 0};
  for (int t = 0; t < 3; t++) {
    u16 *pi = pb[cu], *po = pb[1 - cu];
    u16 *oi = ob[cu], *oo = ob[1 - cu];
    u16 *li = lb[cu], *lo = lb[1 - cu];
    sage_node<<<bP, 256, 0, stream>>>(pi, po, NP, 1.f / 3.f, Wl, bl, Wr, t, 3, relsP,
        pi, off + o0, csr0, NP,
        oi, off + o2, csr2, NO,
        li, off + o4, csr4, NL);
    sage_node<<<bO, 256, 0, stream>>>(oi, oo, NO, 1.f, Wl, bl, Wr, t, 1, relsO,
        pi, off + o1, csr1, NP,
        (const u16*)0, (const int*)0, (const int*)0, 0,
        (const u16*)0, (const int*)0, (const int*)0, 0);
    sage_node<<<bL, 256, 0, stream>>>(li, lo, NL, 1.f, Wl, bl, Wr, t, 1, relsL,
        pi, off + o3, csr3, NP,
        (const u16*)0, (const int*)0, (const int*)0, 0,
        (const u16*)0, (const int*)0, (const int*)0, 0);
    cu = 1 - cu;
  }
  u16* pF = pb[cu];
  u16* oF = ob[cu];
  u16* lF = lb[cu];

  // ---- readout (FP32 output) ----
  colsum2<<<512, 256, 0, stream>>>(pF, NP, gsum);
  colsum2<<<512, 256, 0, stream>>>(oF, NO, gsum + 64);
  colsum2<<<256, 256, 0, stream>>>(lF, NL, gsum + 128);
  head2<<<1, 256, 0, stream>>>(gsum, Wc1, bc1, Wc2, bc2, NP, NO, NL, out);
  suspect2<<<(NP + 255) / 256, 256, 0, stream>>>(pF, Ws1, bs1, Ws2, bs2, out + 20, NP);
}